// Round 5
// baseline (1907.150 us; speedup 1.0000x reference)
//
#include <hip/hip_runtime.h>
#include <cstdint>
#include <cstddef>

#define NEXP 8
#define NBLK 256

typedef __attribute__((ext_vector_type(8))) short short8;
typedef __attribute__((ext_vector_type(4))) float f32x4;

static __device__ __forceinline__ float bf2f(unsigned short u) {
  union { unsigned int i; float f; } v; v.i = ((unsigned int)u) << 16; return v.f;
}
static __device__ __forceinline__ unsigned short f2bf(float f) {
  union { float f; unsigned int i; } v; v.f = f;
  unsigned int x = v.i;
  return (unsigned short)((x + 0x7fffu + ((x >> 16) & 1u)) >> 16);
}

// fast exact-enough GELU: tanh form, |err| <~1e-3 (below bf16 storage quant)
static __device__ __forceinline__ float gelu_fast(float x) {
  const float u = 0.7978845608028654f * (x + 0.044715f * x * x * x);
  const float t = 1.0f - 2.0f / (__expf(2.0f * u) + 1.0f);
  return 0.5f * x * (1.0f + t);
}

__device__ __forceinline__ void gload16(const void* g, void* l) {
  __builtin_amdgcn_global_lo\
ad_lds(
      (const __attribute__((address_space(1))) void*)g,
      (__attribute__((address_space(3))) void*)l, 16, 0, 0);
}

#define BAR() __builtin_amdgcn_s_barrier()
#define WAIT_LGKM0() asm volatile("s_waitcnt lgkmcnt(0)" ::: "memory")

// ---------------------------------------------------------------------------
// software grid barrier: one counter per phase (zeroed by hipMemsetAsync each
// launch). release fence -> arrive -> spin -> acquire fence. All 256 blocks
// are co-resident (1 block/CU via 128KB LDS), so the spin cannot deadlock.
// ---------------------------------------------------------------------------
__device__ __forceinline__ void gridbar(int* bar, int idx) {
  __syncthreads();
  if (threadIdx.x == 0) {
    __threadfence();                    // release: flush this XCD's writes
    atomicAdd(&bar[idx], 1);
    while (atomicAdd(&bar[idx], 0) < NBLK) __builtin_amdgcn_s_sleep(8);
    __threadfence();                    // acquire: invalidate stale L1/L2
  }
  __syncthreads();
}

// ---------------------------------------------------------------------------
// 256x256 8-phase grouped bf16 GEMM phase (T2+T3+T4+T5).
// Block owns expert e = bid&7 (== its XCD); iterates mt/8 tiles with a FIXED
// A m-panel (L2-resident across its n-tiles). Body identical to round-4's
// verified gemm8_kernel.
// ---------------------------------------------------------------------------
template <bool GELU>
__device__ void gemm_phase(
    unsigned short* lds,
    const unsigned short* __restrict__ A,
    const unsigned short* __restrict__ Bt,
    const float* __restrict__ bias,
    unsigned short* __restrict__ C,
    long long strideAe, long long strideCe,
    int mt, int bid, int t)
{
  const int e   = bid & 7;
  const int sub = bid >> 3;   // 0..31
  const int l   = t & 63;
  const int wid = t >> 6;
  const int wm  = wid >> 2;   // 0..1
  const int wn  = wid & 3;    // 0..3

  // staging: dest idx {t, t+512} of a 128x64 half-region (linear LDS dest;
  // source slot = destslot ^ (row&7))
  const int sr = t >> 3;
  const int ss = ((t & 7) ^ ((t >> 3) & 7)) * 8;

  // ds-read swizzled slots: wanted slot ks*4 + (l>>4), XOR (l&7)
  const int kq  = (l >> 4) ^ (l & 3);
  const int b2p = (l >> 2) & 1;
  const int sl0 = ((b2p << 2) | kq) * 8;
  const int sl1 = (((b2p ^ 1) << 2) | kq) * 8;
  const int aR = wm * 8192 + (l & 15) * 64;
  const int bR = 16384 + (wn >> 1) * 8192 + (wn & 1) * 4096 + (l & 15) * 64;

  const int ntile = mt >> 3;  // tiles per block (4 at Bc=8192)
#pragma unroll 1
  for (int r = 0; r < ntile; ++r) {
    const int tau = r * 32 + sub;
    const int m0  = (tau % mt) << 8;   // fixed per block when mt==32
    const int n0  = (tau / mt) << 8;

    const unsigned short* Ae = A + (size_t)e * strideAe + (size_t)m0 * 1024;
    const unsigned short* Be = Bt + ((size_t)e << 20) + (size_t)n0 * 1024;

    auto stageA = [&](int d, int h, int T) {
      const unsigned short* g = Ae + (size_t)(h * 128 + sr) * 1024 + T * 64 + ss;
      unsigned short* lp = lds + d * 32768 + h * 8192 + t * 8;
      gload16(g, lp);
      gload16(g + 65536, lp + 4096);
    };
    auto stageB = [&](int d, int h, int T) {
      const unsigned short* g = Be + (size_t)(h * 128 + sr) * 1024 + T * 64 + ss;
      unsigned short* lp = lds + 16384 + d * 32768 + h * 8192 + t * 8;
      gload16(g, lp);
      gload16(g + 65536, lp + 4096);
    };

    short8 a[4][2], b0[2][2], b1[2][2];
    f32x4 acc[8][4];
#pragma unroll
    for (int i = 0; i < 8; ++i)
#pragma unroll
      for (int j = 0; j < 4; ++j) acc[i][j] = (f32x4){0.f, 0.f, 0.f, 0.f};

    auto ldA = [&](int d, int q) {
#pragma unroll
      for (int m = 0; m < 4; ++m) {
        const unsigned short* p = lds + d * 32768 + aR + (q * 4 + m) * 1024;
        a[m][0] = *(const short8*)(p + sl0);
        a[m][1] = *(const short8*)(p + sl1);
      }
    };
    auto ldB = [&](int d, int q, short8 (&br)[2][2]) {
#pragma unroll
      for (int n = 0; n < 2; ++n) {
        const unsigned short* p = lds + d * 32768 + bR + (q * 2 + n) * 1024;
        br[n][0] = *(const short8*)(p + sl0);
        br[n][1] = *(const short8*)(p + sl1);
      }
    };
    auto mmac = [&](int aq, int bq, short8 (&br)[2][2]) {
      __builtin_amdgcn_s_setprio(1);
#pragma unroll
      for (int ks = 0; ks < 2; ++ks)
#pragma unroll
        for (int m = 0; m < 4; ++m)
#pragma unroll
          for (int n = 0; n < 2; ++n)
            acc[aq * 4 + m][bq * 2 + n] = __builtin_amdgcn_mfma_f32_16x16x32_bf16(
                a[m][ks], br[n][ks], acc[aq * 4 + m][bq * 2 + n], 0, 0, 0);
      __builtin_amdgcn_s_setprio(0);
    };

    // prologue
    stageA(0, 0, 0); stageA(0, 1, 0); stageB(0, 0, 0); stageB(0, 1, 0);
    stageB(1, 0, 1); stageB(1, 1, 1); stageA(1, 0, 1);
    asm volatile("s_waitcnt vmcnt(6)" ::: "memory");
    BAR();

#pragma unroll 1
    for (int i = 0; i < 8; ++i) {
      const bool nl = (i < 7);
      const int T1 = 2 * i + 1, T2 = 2 * i + 2, T3 = 2 * i + 3;
      // P1
      ldA(0, 0); ldB(0, 0, b0); stageA(1, 1, T1);
      asm volatile("s_waitcnt lgkmcnt(8)" ::: "memory");
      BAR(); WAIT_LGKM0();
      mmac(0, 0, b0);
      BAR();
      // P2
      ldB(0, 1, b1);
      BAR(); WAIT_LGKM0();
      mmac(0, 1, b1);
      BAR();
      // P3
      ldA(0, 1);
      if (nl) stageB(0, 0, T2);
      BAR(); WAIT_LGKM0();
      mmac(1, 1, b1);
      BAR();
      // P4
      if (nl) { stageB(0, 1, T2); stageA(0, 0, T2); }
      BAR();
      mmac(1, 0, b0);
      if (nl) asm volatile("s_waitcnt vmcnt(6)" ::: "memory");
      else    asm volatile("s_waitcnt vmcnt(0)" ::: "memory");
      BAR();
      // P5
      ldA(1, 0); ldB(1, 0, b0);
      if (nl) stageA(0, 1, T2);
      asm volatile("s_waitcnt lgkmcnt(8)" ::: "memory");
      BAR(); WAIT_LGKM0();
      mmac(0, 0, b0);
      BAR();
      // P6
      ldB(1, 1, b1);
      BAR(); WAIT_LGKM0();
      mmac(0, 1, b1);
      BAR();
      // P7
      ldA(1, 1);
      if (nl) stageB(1, 0, T3);
      BAR(); WAIT_LGKM0();
      mmac(1, 1, b1);
      BAR();
      // P8
      if (nl) { stageB(1, 1, T3); stageA(1, 0, T3); }
      BAR();
      mmac(1, 0, b0);
      if (nl) asm volatile("s_waitcnt vmcnt(6)" ::: "memory");
      BAR();
    }

    // epilogue: C/D layout col = lane&15, row = (lane>>4)*4 + reg
    const float* bp = bias + (size_t)e * 1024 + n0 + wn * 64;
    unsigned short* Ce = C + (size_t)e * strideCe + (size_t)(m0 + wm * 128) * 1024 + n0 + wn * 64;
    const int cr = (l >> 4) * 4, cc = l & 15;
#pragma unroll
    for (int mi = 0; mi < 8; ++mi) {
#pragma unroll
      for (int ni = 0; ni < 4; ++ni) {
        const int col = ni * 16 + cc;
        const float bv = bp[col];
#pragma unroll
        for (int rr = 0; rr < 4; ++rr) {
          float v = acc[mi][ni][rr] + bv;
          if (GELU) v = gelu_fast(v);
          Ce[(size_t)(mi * 16 + cr + rr) * 1024 + col] = f2bf(v);
        }
      }
    }
  }
}

// ---------------------------------------------------------------------------
// finalize phase: per-expert LayerNorm + softmax-weighted sum, Bc/256 rows/blk
// ---------------------------------------------------------------------------
__device__ void finalize_phase(
    char* smem, const unsigned short* __restrict__ y, const float* __restrict__ wts,
    const float* __restrict__ gamma, const float* __restrict__ beta,
    float* __restrict__ zout, int Bc, int bbase, int bid, int t)
{
  float (*zacc)[1024] = (float(*)[1024])smem;
  const int e = t >> 6;
  const int lane = t & 63;
  const int rows = Bc >> 8;
#pragma unroll 1
  for (int i = 0; i < rows; ++i) {
    const int brow = bid * rows + i;
    __syncthreads();   // zacc safe to overwrite (prev iter's readers done)

    const unsigned short* yp = y + ((size_t)e * Bc + brow) * 1024;
    short8 v0 = *(const short8*)(yp + lane * 8);
    short8 v1 = *(const short8*)(yp + 512 + lane * 8);

    float f0[8], f1[8];
    float s = 0.f, sq = 0.f;
#pragma unroll
    for (int j = 0; j < 8; ++j) {
      f0[j] = bf2f((unsigned short)v0[j]);
      f1[j] = bf2f((unsigned short)v1[j]);
      s += f0[j] + f1[j];
      sq += f0[j] * f0[j] + f1[j] * f1[j];
    }
#pragma unroll
    for (int off = 32; off; off >>= 1) {
      s  += __shfl_xor(s, off);
      sq += __shfl_xor(sq, off);
    }
    const float mu  = s * (1.f / 1024.f);
    const float var = sq * (1.f / 1024.f) - mu * mu;
    const float rs  = rsqrtf(var + 1e-5f);
    const float w   = wts[(size_t)(bbase + brow) * NEXP + e];

    const int c0 = lane * 8;
#pragma unroll
    for (int j = 0; j < 8; ++j) {
      const int ca = c0 + j, cb = 512 + c0 + j;
      zacc[e][ca] = w * ((f0[j] - mu) * rs * gamma[e * 1024 + ca] + beta[e * 1024 + ca]);
      zacc[e][cb] = w * ((f1[j] - mu) * rs * gamma[e * 1024 + cb] + beta[e * 1024 + cb]);
    }
    __syncthreads();
    float r0 = 0.f, r1 = 0.f;
#pragma unroll
    for (int ee = 0; ee < NEXP; ++ee) { r0 += zacc[ee][t]; r1 += zacc[ee][t + 512]; }
    float* zp = zout + (size_t)(bbase + brow) * 1024;
    zp[t] = r0;
    zp[t + 512] = r1;
  }
}

// ---------------------------------------------------------------------------
// persistent mega-kernel: prep -> [g1 -> g2 -> finalize] x nch, grid barriers
// between phases. 256 blocks x 512 threads, 128KB LDS => 1 block/CU.
// ---------------------------------------------------------------------------
__global__ __launch_bounds__(512, 2) void moe_kernel(
    const float* __restrict__ z_s, const float* __restrict__ z_e,
    const float* __restrict__ rw, const float* __restrict__ rb,
    const float* __restrict__ w1, const float* __restrict__ b1,
    const float* __restrict__ w2, const float* __restrict__ b2,
    const float* __restrict__ gamma, const float* __restrict__ beta,
    unsigned short* __restrict__ Xb, float* __restrict__ wts,
    unsigned short* __restrict__ W1t, unsigned short* __restrict__ W2t,
    unsigned short* __restrict__ hbuf, unsigned short* __restrict__ ybuf,
    float* __restrict__ zout, int* bar, int nch, int Bc)
{
  __shared__ __align__(16) char smem[131072];
  unsigned short* lds = (unsigned short*)smem;
  const int bid = blockIdx.x;
  const int t = threadIdx.x;
  const int mt = Bc >> 8;

  // ---- P0a: cast concat rows -> bf16 X + router softmax (wave per row) ----
  {
    const int wv = t >> 6, l = t & 63;
#pragma unroll 1
    for (int i = 0; i < 8; ++i) {
      const int row = bid * 64 + i * 8 + wv;
      const int k0 = l * 16;
      const float* zp = (l < 32) ? (z_s + (size_t)row * 512 + k0)
                                 : (z_e + (size_t)row * 512 + (k0 - 512));
      const float4* zp4 = (const float4*)zp;
      float4 va = zp4[0], vb = zp4[1], vc = zp4[2], vd = zp4[3];
      const float x[16] = { va.x, va.y, va.z, va.w, vb.x, vb.y, vb.z, vb.w,
                            vc.x, vc.y, vc.z, vc.w, vd.x, vd.y, vd.z, vd.w };
      short8 s0, s1;
#pragma unroll
      for (int j = 0; j < 8; ++j) {
        s0[j] = (short)f2bf(x[j]);
        s1[j] = (short)f2bf(x[j + 8]);
      }
      *(short8*)(Xb + (size_t)row * 1024 + k0) = s0;
      *(short8*)(Xb + (size_t)row * 1024 + k0 + 8) = s1;

      float acc[NEXP];
#pragma unroll
      for (int e2 = 0; e2 < NEXP; ++e2) acc[e2] = 0.f;
#pragma unroll
      for (int j = 0; j < 16; ++j) {
        const float4* rp = (const float4*)(rw + (size_t)(k0 + j) * NEXP);
        float4 r0 = rp[0], r1 = rp[1];
        acc[0] += x[j] * r0.x; acc[1] += x[j] * r0.y;
        acc[2] += x[j] * r0.z; acc[3] += x[j] * r0.w;
        acc[4] += x[j] * r1.x; acc[5] += x[j] * r1.y;
        acc[6] += x[j] * r1.z; acc[7] += x[j] * r1.w;
      }
#pragma unroll
      for (int off = 32; off; off >>= 1) {
#pragma unroll
        for (int e2 = 0; e2 < NEXP; ++e2) acc[e2] += __shfl_xor(acc[e2], off);
      }
      if (l < NEXP) {
        float lg[NEXP];
        float mx = -1e30f;
#pragma unroll
        for (int e2 = 0; e2 < NEXP; ++e2) {
          lg[e2] = acc[e2] + rb[e2];
          mx = fmaxf(mx, lg[e2]);
        }
        float sum = 0.f;
#pragma unroll
        for (int e2 = 0; e2 < NEXP; ++e2) sum += expf(lg[e2] - mx);
        wts[(size_t)row * NEXP + l] = expf(lg[l] - mx) / sum;
      }
    }
  }

  // ---- P0b: weight transpose+cast, 64 (32x32) tiles per block, 2 at a time
  {
    unsigned short (*tile)[33] = (unsigned short(*)[33])(smem + (t >> 8) * (32 * 33 * 2));
    const int tt = t & 255;
    const int tx = tt & 31, ty = tt >> 5;
#pragma unroll 1
    for (int it = 0; it < 32; ++it) {
      const int idx = bid * 64 + it * 2 + (t >> 8);
      const int z = idx >> 10, r = idx & 1023;
      const int k0 = (r >> 5) * 32, n0 = (r & 31) * 32;
      const float* w = (z < 8) ? w1 : w2;
      unsigned short* wt = (z < 8) ? W1t : W2t;
      const int e = z & 7;
      __syncthreads();
      const float* wp = w + ((size_t)e << 20) + (size_t)k0 * 1024 + n0;
#pragma unroll
      for (int i = 0; i < 4; ++i) {
        const int kk = ty + i * 8;
        tile[kk][tx] = f2bf(wp[(size_t)kk * 1024 + tx]);
      }
      __syncthreads();
      unsigned short* op = wt + ((size_t)e << 20) + (size_t)n0 * 1024 + k0;
#pragma unroll
      for (int i = 0; i < 4; ++i) {
        const int nn = ty + i * 8;
        op[(size_t)nn * 1024 + tx] = tile[tx][nn];
      }
    }
  }

  int bp = 0;
  gridbar(bar, bp++);

#pragma unroll 1
  for (int c = 0; c < nch; ++c) {
    const int bbase = c * Bc;
    gemm_phase<true>(lds, Xb + (size_t)bbase * 1024, W1t, b1, hbuf,
                     0ll, (long long)Bc * 1024, mt, bid, t);
    gridbar(bar, bp++);
    gemm_phase<false>(lds, hbuf, W2t, b2, ybuf,
                      (long long)Bc * 1024, (long long)Bc * 1024, mt, bid, t);
    gridbar(bar, bp++);
    finalize_phase(smem, ybuf, wts, gamma, beta, zout, Bc, bbase, bid, t);
    if (c + 1 < nch) gridbar(bar, bp++);
  }
}

// ---------------------------------------------------------------------------
extern "C" void kernel_launch(void* const* d_in, const int* in_sizes, int n_in,
                              void* d_out, int out_size, void* d_ws, size_t ws_size,
                              hipStream_t stream)
{
  const float* z_s      = (const float*)d_in[0];
  const float* z_e      = (const float*)d_in[1];
  const float* router_w = (const float*)d_in[2];
  const float* router_b = (const float*)d_in[3];
  const float* w1       = (const float*)d_in[4];
  const float* b1       = (const float*)d_in[5];
  const float* w2       = (const float*)d_in[6];
  const float* b2       = (const float*)d_in[7];
  const float* gamma    = (const float*)d_in[8];
  const float* beta     = (const float*)d_in[9];
  float* zout = (float*)d_out;

  const int B = 16384;

  // workspace layout
  char* ws = (char*)d_ws;
  unsigned short* Xb  = (unsigned short*)ws;                      // 33,554,432 B
  unsigned short* W1t = (unsigned short*)(ws + 33554432);         // 16,777,216 B
  unsigned short* W2t = W1t + ((size_t)8 << 20);                  // 16,777,216 B
  float* wts = (float*)(ws + 33554432 + 2 * 16777216);            //    524,288 B
  int* bar   = (int*)(ws + 33554432 + 2 * 16777216 + 524288);     //        256 B
  const size_t persist = 33554432 + 2 * 16777216 + 524288 + 256;
  char* dyn = ws + persist;
  const size_t rem = (ws_size > persist) ? (ws_size - persist) : 0;

  // nch=2 (Bc=8192) fits the observed ws; grow if ws is smaller.
  int nch = 2;
  while ((size_t)(B / nch) * 32768ull > rem && nch < 8) nch <<= 1;
  const int Bc = B / nch;

  unsigned short* hbuf = (unsigned short*)dyn;
  unsigned short* ybuf = hbuf + (size_t)Bc * 8 * 1024;

  // zero the grid-barrier counters every launch (replay-deterministic)
  hipMemsetAsync(bar, 0, 256, stream);

  moe_kernel<<<NBLK, 512, 0, stream>>>(
      z_s, z_e, router_w, router_b, w1, b1, w2, b2, gamma, beta,
      Xb, wts, W1t, W2t, hbuf, ybuf, zout, bar, nch, Bc);
}

// Round 6
// 1842.409 us; speedup vs baseline: 1.0351x; 1.0351x over previous
//
#include <hip/hip_runtime.h>
#include <cstdint>
#include <cstddef>

#define NEXP 8

typedef __attribute__((ext_vector_type(8))) short short8;
typedef __attribute__((ext_vector_type(4))) float f32x4;

static __device__ __forceinline__ float bf2f(unsigned short u) {
  union { unsigned int i; float f; } v; v.i = ((unsigned int)u) << 16; return v.f;
}
static __device__ __forceinline__ unsigned short f2bf(float f) {
  union { float f; unsigned int i; } v; v.f = f;
  unsigned int x = v.i;
  return (unsigned short)((x + 0x7fffu + ((x >> 16) & 1u)) >> 16);
}

// fast exact-enough GELU: tanh form, |err| <~1e-3 (below bf16 storage quant)
static __device__ __forceinline__ float gelu_fast(float x) {
  const float u = 0.7978845608028654f * (x + 0.044715f * x * x * x);
  const float t = 1.0f - 2.0f / (__expf(2.0f * u) + 1.0f);
  return 0.5f * x * (1.0f + t);
}

__device__ __forceinline__ void gload16(const void* g, void* l) {
  __builtin_amdgcn_global_load_lds(
      (const __attribute__((address_space(1))) void*)g,
      (__attribute__((address_space(3))) void*)l, 16, 0, 0);
}

#define BAR() __builtin_amdgcn_s_barrier()
#define WAIT_LGKM0() asm volatile("s_waitcnt lgkmcnt(0)" ::: "memory")

// ---------------------------------------------------------------------------
// Kernel 1 (merged prep): blocks [0,16384): cast concat row -> bf16 X + router
// softmax; blocks [16384, 32768): transpose+cast w1/w2 -> [E][N][K] bf16.
// ---------------------------------------------------------------------------
__global__ __launch_bounds__(256) void prep_kernel(
    const float* __restrict__ z_s, const float* __restrict__ z_e,
    const float* __restrict__ rw, const float* __restrict__ rb,
    const float* __restrict__ w1, const float* __restrict__ w2,
    unsigned short* __restrict__ Xb, float* __restrict__ wts,
    unsigned short* __restrict__ wt1, unsigned short* __restrict__ wt2)
{
  __shared__ float red[4][NEXP];
  __shared__ unsigned short tile[32][33];
  const int bid = blockIdx.x;
  const int t = threadIdx.x;

  if (bid < 16384) {
    const int b = bid;
    const float* src = (t < 128) ? (z_s + (size_t)b * 512 + t * 4)
                                 : (z_e + (size_t)b * 512 + (t - 128) * 4);
    float4 v = *(const float4*)src;

    ushort4 o;
    o.x = f2bf(v.x); o.y = f2bf(v.y); o.z = f2bf(v.z); o.w = f2bf(v.w);
    *(ushort4*)(Xb + (size_t)b * 1024 + t * 4) = o;

    float acc[NEXP];
#pragma unroll
    for (int e = 0; e < NEXP; ++e) acc[e] = 0.f;

    const int k0 = t * 4;
    const float xv[4] = { v.x, v.y, v.z, v.w };
#pragma unroll
    for (int j = 0; j < 4; ++j) {
      const float x = xv[j];
      const float4* rwp = (const float4*)(rw + (size_t)(k0 + j) * NEXP);
      float4 r0 = rwp[0], r1 = rwp[1];
      acc[0] += x * r0.x; acc[1] += x * r0.y; acc[2] += x * r0.z; acc[3] += x * r0.w;
      acc[4] += x * r1.x; acc[5] += x * r1.y; acc[6] += x * r1.z; acc[7] += x * r1.w;
    }

#pragma unroll
    for (int off = 32; off; off >>= 1) {
#pragma unroll
      for (int e = 0; e < NEXP; ++e) acc[e] += __shfl_xor(acc[e], off);
    }
    if ((t & 63) == 0) {
#pragma unroll
      for (int e = 0; e < NEXP; ++e) red[t >> 6][e] = acc[e];
    }
    __syncthreads();
    if (t == 0) {
      float lg[NEXP];
      float mx = -1e30f;
#pragma unroll
      for (int e = 0; e < NEXP; ++e) {
        lg[e] = red[0][e] + red[1][e] + red[2][e] + red[3][e] + rb[e];
        mx = fmaxf(mx, lg[e]);
      }
      float sum = 0.f;
#pragma unroll
      for (int e = 0; e < NEXP; ++e) { lg[e] = expf(lg[e] - mx); sum += lg[e]; }
      const float inv = 1.f / sum;
#pragma unroll
      for (int e = 0; e < NEXP; ++e) wts[(size_t)b * NEXP + e] = lg[e] * inv;
    }
  } else {
    const int z = (bid - 16384) >> 10;            // 0..15
    const int r = (bid - 16384) & 1023;
    const int k0 = (r >> 5) * 32, n0 = (r & 31) * 32;
    const float* w = (z < 8) ? w1 : w2;
    unsigned short* wt = (z < 8) ? wt1 : wt2;
    const int e = z & 7;
    const int tx = t & 31, ty = t >> 5;

    const float* wp = w + ((size_t)e << 20) + (size_t)k0 * 1024 + n0;
#pragma unroll
    for (int i = 0; i < 4; ++i) {
      const int kk = ty + i * 8;
      tile[kk][tx] = f2bf(wp[(size_t)kk * 1024 + tx]);
    }
    __syncthreads();
    unsigned short* op = wt + ((size_t)e << 20) + (size_t)n0 * 1024 + k0;
#pragma unroll
    for (int i = 0; i < 4; ++i) {
      const int nn = ty + i * 8;
      op[(size_t)nn * 1024 + tx] = tile[tx][nn];
    }
  }
}

// ---------------------------------------------------------------------------
// Kernel 2: 256x256 8-phase bf16 GEMM (T1+T2+T3+T4+T5), K=1024 fixed.
// C[m][n] = A[m][:] . Bt[n][:] + bias[n]  (optional fast GELU)
// 512 threads = 8 waves (2M x 4N); per-wave 128x64 out; BK=64, NT=16, NI=8.
// LDS 128KB double-buffered; XOR swizzle via pre-swizzled global source.
//
// TWO TILES PER BLOCK: same m-panel, adjacent n-tiles (n = 2*np+{0,1}).
// After tile-0's K-loop final barrier the LDS is dead, so tile-1's prologue
// loads are issued BEFORE tile-0's epilogue (stores hide the LDS fill), then
// the standard vmcnt(6)+barrier gate starts tile-1's K-loop. Halves the
// cold-prologue stalls per CU and the block count per dispatch.
//
// grid: 1D nwg = mtiles*16 (pairs: mtiles*2 per expert); XCD-bijective
// swizzle (nwg%8==0); each XCD owns exactly one expert's weight panel.
// ---------------------------------------------------------------------------
template <bool GELU>
__global__ __launch_bounds__(512, 2) void gemm8_kernel(
    const unsigned short* __restrict__ A,
    const unsigned short* __restrict__ Bt,
    const float* __restrict__ bias,
    unsigned short* __restrict__ C,
    long long strideAe, long long strideCe, int mtiles)
{
  __shared__ unsigned short lds[65536];  // 128 KB

  const int nwg = gridDim.x;
  const int cpx = nwg >> 3;
  const int bid = blockIdx.x;
  const int swz = (bid & 7) * cpx + (bid >> 3);
  const int ppe = mtiles << 1;           // tile-pairs per expert
  const int e   = swz / ppe;
  const int rem = swz - e * ppe;
  const int m0  = (rem >> 1) << 8;
  const int np  = rem & 1;               // n-pair: tiles n = 2*np, 2*np+1

  const int t   = threadIdx.x;
  const int l   = t & 63;
  const int wid = t >> 6;
  const int wm  = wid >> 2;   // 0..1
  const int wn  = wid & 3;    // 0..3

  const unsigned short* Ae  = A + (size_t)e * strideAe + (size_t)m0 * 1024;
  const unsigned short* Be0 = Bt + ((size_t)e << 20) + ((size_t)((np << 1) + 0) << 8) * 1024;
  const unsigned short* Be1 = Bt + ((size_t)e << 20) + ((size_t)((np << 1) + 1) << 8) * 1024;

  // staging: dest idx {t, t+512} of a 128x64 half-region (linear LDS dest;
  // source slot = destslot ^ (row&7))
  const int sr = t >> 3;
  const int ss = ((t & 7) ^ ((t >> 3) & 7)) * 8;

  auto stageA = [&](int d, int h, int T) {
    const unsigned short* g = Ae + (size_t)(h * 128 + sr) * 1024 + T * 64 + ss;
    unsigned short* lp = lds + d * 32768 + h * 8192 + t * 8;
    gload16(g, lp);
    gload16(g + 65536, lp + 4096);
  };
  auto stageB = [&](const unsigned short* Be, int d, int h, int T) {
    const unsigned short* g = Be + (size_t)(h * 128 + sr) * 1024 + T * 64 + ss;
    unsigned short* lp = lds + 16384 + d * 32768 + h * 8192 + t * 8;
    gload16(g, lp);
    gload16(g + 65536, lp + 4096);
  };
  // prologue: buf0 all 4 halves first (the vmcnt(6)-gated set), then 3 of buf1
  auto prologue = [&](const unsigned short* Be) {
    stageA(0, 0, 0); stageA(0, 1, 0); stageB(Be, 0, 0, 0); stageB(Be, 0, 1, 0);
    stageB(Be, 1, 0, 1); stageB(Be, 1, 1, 1); stageA(1, 0, 1);
  };

  // ds-read swizzled slots: wanted slot ks*4 + (l>>4), XOR (l&7)
  const int kq  = (l >> 4) ^ (l & 3);
  const int b2p = (l >> 2) & 1;
  const int sl0 = ((b2p << 2) | kq) * 8;
  const int sl1 = (((b2p ^ 1) << 2) | kq) * 8;
  const int aR = wm * 8192 + (l & 15) * 64;
  const int bR = 16384 + (wn >> 1) * 8192 + (wn & 1) * 4096 + (l & 15) * 64;

  short8 a[4][2], b0[2][2], b1[2][2];
  f32x4 acc[8][4];

  auto ldA = [&](int d, int q) {
#pragma unroll
    for (int m = 0; m < 4; ++m) {
      const unsigned short* p = lds + d * 32768 + aR + (q * 4 + m) * 1024;
      a[m][0] = *(const short8*)(p + sl0);
      a[m][1] = *(const short8*)(p + sl1);
    }
  };
  auto ldB = [&](int d, int q, short8 (&br)[2][2]) {
#pragma unroll
    for (int n = 0; n < 2; ++n) {
      const unsigned short* p = lds + d * 32768 + bR + (q * 2 + n) * 1024;
      br[n][0] = *(const short8*)(p + sl0);
      br[n][1] = *(const short8*)(p + sl1);
    }
  };
  auto mmac = [&](int aq, int bq, short8 (&br)[2][2]) {
    __builtin_amdgcn_s_setprio(1);
#pragma unroll
    for (int ks = 0; ks < 2; ++ks)
#pragma unroll
      for (int m = 0; m < 4; ++m)
#pragma unroll
        for (int n = 0; n < 2; ++n)
          acc[aq * 4 + m][bq * 2 + n] = __builtin_amdgcn_mfma_f32_16x16x32_bf16(
              a[m][ks], br[n][ks], acc[aq * 4 + m][bq * 2 + n], 0, 0, 0);
    __builtin_amdgcn_s_setprio(0);
  };

  // tile-0 prologue
  prologue(Be0);
  asm volatile("s_waitcnt vmcnt(6)" ::: "memory");
  BAR();

#pragma unroll 1
  for (int tl = 0; tl < 2; ++tl) {
    const unsigned short* Be = (tl == 0) ? Be0 : Be1;
    const int n0 = ((np << 1) | tl) << 8;

#pragma unroll
    for (int i = 0; i < 8; ++i)
#pragma unroll
      for (int j = 0; j < 4; ++j) acc[i][j] = (f32x4){0.f, 0.f, 0.f, 0.f};

#pragma unroll 1
    for (int i = 0; i < 8; ++i) {
      const bool nl = (i < 7);
      const int T1 = 2 * i + 1, T2 = 2 * i + 2, T3 = 2 * i + 3;
      // P1
      ldA(0, 0); ldB(0, 0, b0); stageA(1, 1, T1);
      asm volatile("s_waitcnt lgkmcnt(8)" ::: "memory");
      BAR(); WAIT_LGKM0();
      mmac(0, 0, b0);
      BAR();
      // P2
      ldB(0, 1, b1);
      BAR(); WAIT_LGKM0();
      mmac(0, 1, b1);
      BAR();
      // P3
      ldA(0, 1);
      if (nl) stageB(Be, 0, 0, T2);
      BAR(); WAIT_LGKM0();
      mmac(1, 1, b1);
      BAR();
      // P4
      if (nl) { stageB(Be, 0, 1, T2); stageA(0, 0, T2); }
      BAR();
      mmac(1, 0, b0);
      if (nl) asm volatile("s_waitcnt vmcnt(6)" ::: "memory");
      else    asm volatile("s_waitcnt vmcnt(0)" ::: "memory");
      BAR();
      // P5
      ldA(1, 0); ldB(1, 0, b0);
      if (nl) stageA(0, 1, T2);
      asm volatile("s_waitcnt lgkmcnt(8)" ::: "memory");
      BAR(); WAIT_LGKM0();
      mmac(0, 0, b0);
      BAR();
      // P6
      ldB(1, 1, b1);
      BAR(); WAIT_LGKM0();
      mmac(0, 1, b1);
      BAR();
      // P7
      ldA(1, 1);
      if (nl) stageB(Be, 1, 0, T3);
      BAR(); WAIT_LGKM0();
      mmac(1, 1, b1);
      BAR();
      // P8
      if (nl) { stageB(Be, 1, 1, T3); stageA(1, 0, T3); }
      BAR();
      mmac(1, 0, b0);
      if (nl) asm volatile("s_waitcnt vmcnt(6)" ::: "memory");
      BAR();
    }
    // after final barrier all LDS reads are done: issue next tile's prologue
    // so its HBM fill hides under this tile's epilogue stores.
    if (tl == 0) prologue(Be1);

    // epilogue: C/D layout col = lane&15, row = (lane>>4)*4 + reg
    const float* bp = bias + (size_t)e * 1024 + n0 + wn * 64;
    unsigned short* Ce = C + (size_t)e * strideCe + (size_t)(m0 + wm * 128) * 1024 + n0 + wn * 64;
    const int cr = (l >> 4) * 4, cc = l & 15;
#pragma unroll
    for (int mi = 0; mi < 8; ++mi) {
#pragma unroll
      for (int ni = 0; ni < 4; ++ni) {
        const int col = ni * 16 + cc;
        const float bv = bp[col];
#pragma unroll
        for (int r = 0; r < 4; ++r) {
          float v = acc[mi][ni][r] + bv;
          if (GELU) v = gelu_fast(v);
          Ce[(size_t)(mi * 16 + cr + r) * 1024 + col] = f2bf(v);
        }
      }
    }

    if (tl == 0) {
      asm volatile("s_waitcnt vmcnt(6)" ::: "memory");
      BAR();
    }
  }
}

// ---------------------------------------------------------------------------
// Kernel 3: per-expert LayerNorm + softmax-weighted sum over experts
// ---------------------------------------------------------------------------
__global__ __launch_bounds__(512) void finalize_kernel(
    const unsigned short* __restrict__ y,   // [E][Bc][1024] bf16
    const float* __restrict__ wts,
    const float* __restrict__ gamma,
    const float* __restrict__ beta,
    float* __restrict__ zout,
    int Bc, int bbase)
{
  __shared__ float zacc[NEXP][1024];
  const int brow = blockIdx.x;
  const int t = threadIdx.x;
  const int e = t >> 6;
  const int lane = t & 63;

  const unsigned short* yp = y + ((size_t)e * Bc + brow) * 1024;
  short8 v0 = *(const short8*)(yp + lane * 8);
  short8 v1 = *(const short8*)(yp + 512 + lane * 8);

  float f0[8], f1[8];
  float s = 0.f, sq = 0.f;
#pragma unroll
  for (int j = 0; j < 8; ++j) {
    f0[j] = bf2f((unsigned short)v0[j]);
    f1[j] = bf2f((unsigned short)v1[j]);
    s += f0[j] + f1[j];
    sq += f0[j] * f0[j] + f1[j] * f1[j];
  }
#pragma unroll
  for (int off = 32; off; off >>= 1) {
    s  += __shfl_xor(s, off);
    sq += __shfl_xor(sq, off);
  }
  const float mu  = s * (1.f / 1024.f);
  const float var = sq * (1.f / 1024.f) - mu * mu;
  const float rs  = rsqrtf(var + 1e-5f);
  const float w   = wts[(size_t)(bbase + brow) * NEXP + e];

  const int c0 = lane * 8;
#pragma unroll
  for (int j = 0; j < 8; ++j) {
    const int ca = c0 + j, cb = 512 + c0 + j;
    zacc[e][ca] = w * ((f0[j] - mu) * rs * gamma[e * 1024 + ca] + beta[e * 1024 + ca]);
    zacc[e][cb] = w * ((f1[j] - mu) * rs * gamma[e * 1024 + cb] + beta[e * 1024 + cb]);
  }
  __syncthreads();
  float r0 = 0.f, r1 = 0.f;
#pragma unroll
  for (int ee = 0; ee < NEXP; ++ee) { r0 += zacc[ee][t]; r1 += zacc[ee][t + 512]; }
  float* zp = zout + (size_t)(bbase + brow) * 1024;
  zp[t] = r0;
  zp[t + 512] = r1;
}

// ---------------------------------------------------------------------------
extern "C" void kernel_launch(void* const* d_in, const int* in_sizes, int n_in,
                              void* d_out, int out_size, void* d_ws, size_t ws_size,
                              hipStream_t stream)
{
  const float* z_s      = (const float*)d_in[0];
  const float* z_e      = (const float*)d_in[1];
  const float* router_w = (const float*)d_in[2];
  const float* router_b = (const float*)d_in[3];
  const float* w1       = (const float*)d_in[4];
  const float* b1       = (const float*)d_in[5];
  const float* w2       = (const float*)d_in[6];
  const float* b2       = (const float*)d_in[7];
  const float* gamma    = (const float*)d_in[8];
  const float* beta     = (const float*)d_in[9];
  float* zout = (float*)d_out;

  const int B = 16384;

  // workspace layout
  char* ws = (char*)d_ws;
  unsigned short* Xb  = (unsigned short*)ws;                      // 33,554,432 B
  unsigned short* W1t = (unsigned short*)(ws + 33554432);         // 16,777,216 B
  unsigned short* W2t = W1t + ((size_t)8 << 20);                  // 16,777,216 B
  float* wts = (float*)(ws + 33554432 + 2 * 16777216);            //    524,288 B
  const size_t persist = 33554432 + 2 * 16777216 + 524288;
  char* dyn = ws + persist;
  const size_t rem = (ws_size > persist) ? (ws_size - persist) : 0;

  // nch=2 (Bc=8192): fewest dispatch boundaries that fit ws; h largely
  // L3-resident anyway (round-2 FETCH evidence). Grow nch if ws is small.
  int nch = 2;
  while ((size_t)(B / nch) * 32768ull > rem && nch < 64) nch <<= 1;
  const int Bc = B / nch;   // multiple of 256

  unsigned short* hbuf = (unsigned short*)dyn;
  unsigned short* ybuf = hbuf + (size_t)Bc * 8 * 1024;

  prep_kernel<<<32768, 256, 0, stream>>>(z_s, z_e, router_w, router_b, w1, w2,
                                         Xb, wts, W1t, W2t);

  const int mt = Bc >> 8;        // m-tiles of 256
  const int nwg = mt * 16;       // tile-PAIRS: * 2 n-pairs * 8 experts

  for (int c = 0; c < nch; ++c) {
    const int bbase = c * Bc;
    gemm8_kernel<true><<<nwg, 512, 0, stream>>>(
        Xb + (size_t)bbase * 1024, W1t, b1, hbuf, 0ll, (long long)Bc * 1024, mt);
    gemm8_kernel<false><<<nwg, 512, 0, stream>>>(
        hbuf, W2t, b2, ybuf, (long long)Bc * 1024, (long long)Bc * 1024, mt);
    finalize_kernel<<<Bc, 512, 0, stream>>>(ybuf, wts, gamma, beta, zout, Bc, bbase);
  }
}

// Round 7
// 761.169 us; speedup vs baseline: 2.5056x; 2.4205x over previous
//
#include <hip/hip_runtime.h>
#include <cstdint>
#include <cstddef>

#define NEXP 8

typedef __attribute__((ext_vector_type(8))) short short8;
typedef __attribute__((ext_vector_type(4))) float f32x4;

static __device__ __forceinline__ float bf2f(unsigned short u) {
  union { unsigned int i; float f; } v; v.i = ((unsigned int)u) << 16; return v.f;
}
static __device__ __forceinline__ unsigned short f2bf(float f) {
  union { float f; unsigned int i; } v; v.f = f;
  unsigned int x = v.i;
  return (unsigned short)((x + 0x7fffu + ((x >> 16) & 1u)) >> 16);
}

// fast exact-enough GELU: tanh form, |err| <~1e-3 (below bf16 storage quant)
static __device__ __forceinline__ float gelu_fast(float x) {
  const float u = 0.7978845608028654f * (x + 0.044715f * x * x * x);
  const float t = 1.0f - 2.0f / (__expf(2.0f * u) + 1.0f);
  return 0.5f * x * (1.0f + t);
}

__device__ __forceinline__ void gload16(const void* g, void* l) {
  __builtin_amdgcn_global_load_lds(
      (const __attribute__((address_space(1))) void*)g,
      (__attribute__((address_space(3))) void*)l, 16, 0, 0);
}

#define BAR() __builtin_amdgcn_s_barrier()
#define WAIT_LGKM0() asm volatile("s_waitcnt lgkmcnt(0)" ::: "memory")

// ---------------------------------------------------------------------------
// Kernel 1 (merged prep): blocks [0,16384): cast concat row -> bf16 X + router
// softmax; blocks [16384, 32768): transpose+cast w1/w2 -> [E][N][K] bf16.
// ---------------------------------------------------------------------------
__global__ __launch_bounds__(256) void prep_kernel(
    const float* __restrict__ z_s, const float* __restrict__ z_e,
    const float* __restrict__ rw, const float* __restrict__ rb,
    const float* __restrict__ w1, const float* __restrict__ w2,
    unsigned short* __restrict__ Xb, float* __restrict__ wts,
    unsigned short* __restrict__ wt1, unsigned short* __restrict__ wt2)
{
  __shared__ float red[4][NEXP];
  __shared__ unsigned short tile[32][33];
  const int bid = blockIdx.x;
  const int t = threadIdx.x;

  if (bid < 16384) {
    const int b = bid;
    const float* src = (t < 128) ? (z_s + (size_t)b * 512 + t * 4)
                                 : (z_e + (size_t)b * 512 + (t - 128) * 4);
    float4 v = *(const float4*)src;

    ushort4 o;
    o.x = f2bf(v.x); o.y = f2bf(v.y); o.z = f2bf(v.z); o.w = f2bf(v.w);
    *(ushort4*)(Xb + (size_t)b * 1024 + t * 4) = o;

    float acc[NEXP];
#pragma unroll
    for (int e = 0; e < NEXP; ++e) acc[e] = 0.f;

    const int k0 = t * 4;
    const float xv[4] = { v.x, v.y, v.z, v.w };
#pragma unroll
    for (int j = 0; j < 4; ++j) {
      const float x = xv[j];
      const float4* rwp = (const float4*)(rw + (size_t)(k0 + j) * NEXP);
      float4 r0 = rwp[0], r1 = rwp[1];
      acc[0] += x * r0.x; acc[1] += x * r0.y; acc[2] += x * r0.z; acc[3] += x * r0.w;
      acc[4] += x * r1.x; acc[5] += x * r1.y; acc[6] += x * r1.z; acc[7] += x * r1.w;
    }

#pragma unroll
    for (int off = 32; off; off >>= 1) {
#pragma unroll
      for (int e = 0; e < NEXP; ++e) acc[e] += __shfl_xor(acc[e], off);
    }
    if ((t & 63) == 0) {
#pragma unroll
      for (int e = 0; e < NEXP; ++e) red[t >> 6][e] = acc[e];
    }
    __syncthreads();
    if (t == 0) {
      float lg[NEXP];
      float mx = -1e30f;
#pragma unroll
      for (int e = 0; e < NEXP; ++e) {
        lg[e] = red[0][e] + red[1][e] + red[2][e] + red[3][e] + rb[e];
        mx = fmaxf(mx, lg[e]);
      }
      float sum = 0.f;
#pragma unroll
      for (int e = 0; e < NEXP; ++e) { lg[e] = expf(lg[e] - mx); sum += lg[e]; }
      const float inv = 1.f / sum;
#pragma unroll
      for (int e = 0; e < NEXP; ++e) wts[(size_t)b * NEXP + e] = lg[e] * inv;
    }
  } else {
    const int z = (bid - 16384) >> 10;            // 0..15
    const int r = (bid - 16384) & 1023;
    const int k0 = (r >> 5) * 32, n0 = (r & 31) * 32;
    const float* w = (z < 8) ? w1 : w2;
    unsigned short* wt = (z < 8) ? wt1 : wt2;
    const int e = z & 7;
    const int tx = t & 31, ty = t >> 5;

    const float* wp = w + ((size_t)e << 20) + (size_t)k0 * 1024 + n0;
#pragma unroll
    for (int i = 0; i < 4; ++i) {
      const int kk = ty + i * 8;
      tile[kk][tx] = f2bf(wp[(size_t)kk * 1024 + tx]);
    }
    __syncthreads();
    unsigned short* op = wt + ((size_t)e << 20) + (size_t)n0 * 1024 + k0;
#pragma unroll
    for (int i = 0; i < 4; ++i) {
      const int nn = ty + i * 8;
      op[(size_t)nn * 1024 + tx] = tile[tx][nn];
    }
  }
}

// ---------------------------------------------------------------------------
// Kernel 2: 256x256 8-phase bf16 GEMM (T1+T2+T3+T4+T5), K=1024 fixed.
// C[m][n] = A[m][:] . Bt[n][:] + bias[n]  (optional fast GELU)
// 512 threads = 8 waves (2M x 4N); per-wave 128x64 out; BK=64, NT=16, NI=8.
// LDS 128KB double-buffered; XOR swizzle via pre-swizzled global source.
// grid: 1D nwg = mtiles*4*8; XCD-bijective swizzle (nwg%8==0).
// ONE tile per block (R6's 2-tile pairing caused partial-line C-store RMW
// amplification: FETCH 49->211 MB, WRITE 65->376 MB — do not reintroduce).
// ---------------------------------------------------------------------------
template <bool GELU>
__global__ __launch_bounds__(512, 2) void gemm8_kernel(
    const unsigned short* __restrict__ A,
    const unsigned short* __restrict__ Bt,
    const float* __restrict__ bias,
    unsigned short* __restrict__ C,
    long long strideAe, long long strideCe, int mtiles)
{
  __shared__ unsigned short lds[65536];  // 128 KB

  const int nwg = gridDim.x;
  const int cpx = nwg >> 3;
  const int bid = blockIdx.x;
  const int swz = (bid & 7) * cpx + (bid >> 3);
  const int e   = swz / (mtiles << 2);
  const int rem = swz - e * (mtiles << 2);
  const int m0  = (rem >> 2) << 8;
  const int n0  = (rem & 3) << 8;

  const int t   = threadIdx.x;
  const int l   = t & 63;
  const int wid = t >> 6;
  const int wm  = wid >> 2;   // 0..1
  const int wn  = wid & 3;    // 0..3

  const unsigned short* Ae = A + (size_t)e * strideAe + (size_t)m0 * 1024;
  const unsigned short* Be = Bt + ((size_t)e << 20) + (size_t)n0 * 1024;

  // staging: dest idx {t, t+512} of a 128x64 half-region (linear LDS dest;
  // source slot = destslot ^ (row&7))
  const int sr = t >> 3;
  const int ss = ((t & 7) ^ ((t >> 3) & 7)) * 8;

  auto stageA = [&](int d, int h, int T) {
    const unsigned short* g = Ae + (size_t)(h * 128 + sr) * 1024 + T * 64 + ss;
    unsigned short* lp = lds + d * 32768 + h * 8192 + t * 8;
    gload16(g, lp);
    gload16(g + 65536, lp + 4096);
  };
  auto stageB = [&](int d, int h, int T) {
    const unsigned short* g = Be + (size_t)(h * 128 + sr) * 1024 + T * 64 + ss;
    unsigned short* lp = lds + 16384 + d * 32768 + h * 8192 + t * 8;
    gload16(g, lp);
    gload16(g + 65536, lp + 4096);
  };

  // ds-read swizzled slots: wanted slot ks*4 + (l>>4), XOR (l&7)
  const int kq  = (l >> 4) ^ (l & 3);
  const int b2p = (l >> 2) & 1;
  const int sl0 = ((b2p << 2) | kq) * 8;
  const int sl1 = (((b2p ^ 1) << 2) | kq) * 8;
  const int aR = wm * 8192 + (l & 15) * 64;
  const int bR = 16384 + (wn >> 1) * 8192 + (wn & 1) * 4096 + (l & 15) * 64;

  short8 a[4][2], b0[2][2], b1[2][2];
  f32x4 acc[8][4];
#pragma unroll
  for (int i = 0; i < 8; ++i)
#pragma unroll
    for (int j = 0; j < 4; ++j) acc[i][j] = (f32x4){0.f, 0.f, 0.f, 0.f};

  auto ldA = [&](int d, int q) {
#pragma unroll
    for (int m = 0; m < 4; ++m) {
      const unsigned short* p = lds + d * 32768 + aR + (q * 4 + m) * 1024;
      a[m][0] = *(const short8*)(p + sl0);
      a[m][1] = *(const short8*)(p + sl1);
    }
  };
  auto ldB = [&](int d, int q, short8 (&br)[2][2]) {
#pragma unroll
    for (int n = 0; n < 2; ++n) {
      const unsigned short* p = lds + d * 32768 + bR + (q * 2 + n) * 1024;
      br[n][0] = *(const short8*)(p + sl0);
      br[n][1] = *(const short8*)(p + sl1);
    }
  };
  auto mmac = [&](int aq, int bq, short8 (&br)[2][2]) {
    __builtin_amdgcn_s_setprio(1);
#pragma unroll
    for (int ks = 0; ks < 2; ++ks)
#pragma unroll
      for (int m = 0; m < 4; ++m)
#pragma unroll
        for (int n = 0; n < 2; ++n)
          acc[aq * 4 + m][bq * 2 + n] = __builtin_amdgcn_mfma_f32_16x16x32_bf16(
              a[m][ks], br[n][ks], acc[aq * 4 + m][bq * 2 + n], 0, 0, 0);
    __builtin_amdgcn_s_setprio(0);
  };

  // prologue
  stageA(0, 0, 0); stageA(0, 1, 0); stageB(0, 0, 0); stageB(0, 1, 0);
  stageB(1, 0, 1); stageB(1, 1, 1); stageA(1, 0, 1);
  asm volatile("s_waitcnt vmcnt(6)" ::: "memory");
  BAR();

#pragma unroll 1
  for (int i = 0; i < 8; ++i) {
    const bool nl = (i < 7);
    const int T1 = 2 * i + 1, T2 = 2 * i + 2, T3 = 2 * i + 3;
    // P1
    ldA(0, 0); ldB(0, 0, b0); stageA(1, 1, T1);
    asm volatile("s_waitcnt lgkmcnt(8)" ::: "memory");
    BAR(); WAIT_LGKM0();
    mmac(0, 0, b0);
    BAR();
    // P2
    ldB(0, 1, b1);
    BAR(); WAIT_LGKM0();
    mmac(0, 1, b1);
    BAR();
    // P3
    ldA(0, 1);
    if (nl) stageB(0, 0, T2);
    BAR(); WAIT_LGKM0();
    mmac(1, 1, b1);
    BAR();
    // P4
    if (nl) { stageB(0, 1, T2); stageA(0, 0, T2); }
    BAR();
    mmac(1, 0, b0);
    if (nl) asm volatile("s_waitcnt vmcnt(6)" ::: "memory");
    else    asm volatile("s_waitcnt vmcnt(0)" ::: "memory");
    BAR();
    // P5
    ldA(1, 0); ldB(1, 0, b0);
    if (nl) stageA(0, 1, T2);
    asm volatile("s_waitcnt lgkmcnt(8)" ::: "memory");
    BAR(); WAIT_LGKM0();
    mmac(0, 0, b0);
    BAR();
    // P6
    ldB(1, 1, b1);
    BAR(); WAIT_LGKM0();
    mmac(0, 1, b1);
    BAR();
    // P7
    ldA(1, 1);
    if (nl) stageB(1, 0, T3);
    BAR(); WAIT_LGKM0();
    mmac(1, 1, b1);
    BAR();
    // P8
    if (nl) { stageB(1, 1, T3); stageA(1, 0, T3); }
    BAR();
    mmac(1, 0, b0);
    if (nl) asm volatile("s_waitcnt vmcnt(6)" ::: "memory");
    BAR();
  }

  // epilogue: C/D layout col = lane&15, row = (lane>>4)*4 + reg
  const float* bp = bias + (size_t)e * 1024 + n0 + wn * 64;
  unsigned short* Ce = C + (size_t)e * strideCe + (size_t)(m0 + wm * 128) * 1024 + n0 + wn * 64;
  const int cr = (l >> 4) * 4, cc = l & 15;
#pragma unroll
  for (int mi = 0; mi < 8; ++mi) {
#pragma unroll
    for (int ni = 0; ni < 4; ++ni) {
      const int col = ni * 16 + cc;
      const float bv = bp[col];
#pragma unroll
      for (int r = 0; r < 4; ++r) {
        float v = acc[mi][ni][r] + bv;
        if (GELU) v = gelu_fast(v);
        Ce[(size_t)(mi * 16 + cr + r) * 1024 + col] = f2bf(v);
      }
    }
  }
}

// ---------------------------------------------------------------------------
// Kernel 3: per-expert LayerNorm + softmax-weighted sum over experts
// ---------------------------------------------------------------------------
__global__ __launch_bounds__(512) void finalize_kernel(
    const unsigned short* __restrict__ y,   // [E][Bc][1024] bf16
    const float* __restrict__ wts,
    const float* __restrict__ gamma,
    const float* __restrict__ beta,
    float* __restrict__ zout,
    int Bc, int bbase)
{
  __shared__ float zacc[NEXP][1024];
  const int brow = blockIdx.x;
  const int t = threadIdx.x;
  const int e = t >> 6;
  const int lane = t & 63;

  const unsigned short* yp = y + ((size_t)e * Bc + brow) * 1024;
  short8 v0 = *(const short8*)(yp + lane * 8);
  short8 v1 = *(const short8*)(yp + 512 + lane * 8);

  float f0[8], f1[8];
  float s = 0.f, sq = 0.f;
#pragma unroll
  for (int j = 0; j < 8; ++j) {
    f0[j] = bf2f((unsigned short)v0[j]);
    f1[j] = bf2f((unsigned short)v1[j]);
    s += f0[j] + f1[j];
    sq += f0[j] * f0[j] + f1[j] * f1[j];
  }
#pragma unroll
  for (int off = 32; off; off >>= 1) {
    s  += __shfl_xor(s, off);
    sq += __shfl_xor(sq, off);
  }
  const float mu  = s * (1.f / 1024.f);
  const float var = sq * (1.f / 1024.f) - mu * mu;
  const float rs  = rsqrtf(var + 1e-5f);
  const float w   = wts[(size_t)(bbase + brow) * NEXP + e];

  const int c0 = lane * 8;
#pragma unroll
  for (int j = 0; j < 8; ++j) {
    const int ca = c0 + j, cb = 512 + c0 + j;
    zacc[e][ca] = w * ((f0[j] - mu) * rs * gamma[e * 1024 + ca] + beta[e * 1024 + ca]);
    zacc[e][cb] = w * ((f1[j] - mu) * rs * gamma[e * 1024 + cb] + beta[e * 1024 + cb]);
  }
  __syncthreads();
  float r0 = 0.f, r1 = 0.f;
#pragma unroll
  for (int ee = 0; ee < NEXP; ++ee) { r0 += zacc[ee][t]; r1 += zacc[ee][t + 512]; }
  float* zp = zout + (size_t)(bbase + brow) * 1024;
  zp[t] = r0;
  zp[t + 512] = r1;
}

// ---------------------------------------------------------------------------
extern "C" void kernel_launch(void* const* d_in, const int* in_sizes, int n_in,
                              void* d_out, int out_size, void* d_ws, size_t ws_size,
                              hipStream_t stream)
{
  const float* z_s      = (const float*)d_in[0];
  const float* z_e      = (const float*)d_in[1];
  const float* router_w = (const float*)d_in[2];
  const float* router_b = (const float*)d_in[3];
  const float* w1       = (const float*)d_in[4];
  const float* b1       = (const float*)d_in[5];
  const float* w2       = (const float*)d_in[6];
  const float* b2       = (const float*)d_in[7];
  const float* gamma    = (const float*)d_in[8];
  const float* beta     = (const float*)d_in[9];
  float* zout = (float*)d_out;

  const int B = 16384;

  // workspace layout
  char* ws = (char*)d_ws;
  unsigned short* Xb  = (unsigned short*)ws;                      // 33,554,432 B
  unsigned short* W1t = (unsigned short*)(ws + 33554432);         // 16,777,216 B
  unsigned short* W2t = W1t + ((size_t)8 << 20);                  // 16,777,216 B
  float* wts = (float*)(ws + 33554432 + 2 * 16777216);            //    524,288 B
  const size_t persist = 33554432 + 2 * 16777216 + 524288;
  char* dyn = ws + persist;
  const size_t rem = (ws_size > persist) ? (ws_size - persist) : 0;

  // nch=2 (Bc=8192): fewest dispatch boundaries that fit ws; h largely
  // L3-resident anyway (round-2 FETCH evidence). Grow nch if ws is small.
  int nch = 2;
  while ((size_t)(B / nch) * 32768ull > rem && nch < 64) nch <<= 1;
  const int Bc = B / nch;   // multiple of 256

  unsigned short* hbuf = (unsigned short*)dyn;
  unsigned short* ybuf = hbuf + (size_t)Bc * 8 * 1024;

  prep_kernel<<<32768, 256, 0, stream>>>(z_s, z_e, router_w, router_b, w1, w2,
                                         Xb, wts, W1t, W2t);

  const int mt = Bc >> 8;        // m-tiles of 256
  const int nwg = mt * 32;       // * 4 n-tiles * 8 experts

  for (int c = 0; c < nch; ++c) {
    const int bbase = c * Bc;
    gemm8_kernel<true><<<nwg, 512, 0, stream>>>(
        Xb + (size_t)bbase * 1024, W1t, b1, hbuf, 0ll, (long long)Bc * 1024, mt);
    gemm8_kernel<false><<<nwg, 512, 0, stream>>>(
        hbuf, W2t, b2, ybuf, (long long)Bc * 1024, (long long)Bc * 1024, mt);
    finalize_kernel<<<Bc, 512, 0, stream>>>(ybuf, wts, gamma, beta, zout, Bc, bbase);
  }
}